// Round 12
// baseline (383.615 us; speedup 1.0000x reference)
//
#include <hip/hip_runtime.h>

#define BB 4096
#define TT 256
#define FF 32
#define HH 6

#define DPP_XOR1 0xB1   // quad_perm(1,0,3,2)
#define DPP_XOR2 0x4E   // quad_perm(2,3,0,1)
#define DPP_XOR3 0x1B   // quad_perm(3,2,1,0)
#define DPP_HALF 0x141  // row_half_mirror = xor 7 within 8-lane half-rows

__device__ __forceinline__ float fast_rcp(float x) { return __builtin_amdgcn_rcpf(x); }
__device__ __forceinline__ float sigmoidf(float x) { return fast_rcp(1.0f + __expf(-x)); }

template <int CTRL>
__device__ __forceinline__ float dppf(float x) {
    return __int_as_float(__builtin_amdgcn_update_dpp(
        0, __float_as_int(x), CTRL, 0xF, 0xF, true));
}
__device__ __forceinline__ float dpp_xor4(float x) {
    return dppf<DPP_HALF>(dppf<DPP_XOR3>(x));
}

// K0: transpose Wa (32x32) into ws so K1 can read score-columns as rows.
__global__ void k_transpose(const float* __restrict__ Wa, float* __restrict__ WaT) {
    const int i = threadIdx.x;                 // 256 threads x 4 elements
#pragma unroll
    for (int k = 0; k < 4; ++k) {
        const int idx = i * 4 + k;             // 0..1023
        const int r = idx >> 5, c = idx & 31;
        WaT[c * 32 + r] = Wa[r * 32 + c];
    }
}

// K1: 1 thread per (b,t); single-pass streaming attention+projection.
// Per score column F2 (macro-expanded, ALL literal indices -> no scratch):
//   dot = ba[F2] + x . WaT[F2,:]   (weights: wave-uniform s_load rows)
//   e = exp(dot); sum += e; acc[:] += (x[F2]*e) * Wl[F2,:]
// Epilogue: acc*(1/sum) + bl, gate-major -> [unit][i,f,g,o] (verified R10).
// Live set ~62 regs: xv[32]+acc[24]+transients. No s[]/e[] arrays at all.
__global__ __launch_bounds__(256, 4) void k_attn_xz(
    const float* __restrict__ x, const float* __restrict__ WaT, const float* __restrict__ ba,
    const float* __restrict__ Wl, const float* __restrict__ bl, float* __restrict__ xz)
{
    const int tid = blockIdx.x * 256 + threadIdx.x;
    const float* xp = x + (size_t)tid * FF;

    float xv[FF];
#pragma unroll
    for (int c = 0; c < FF / 4; ++c) {
        const float4 v = *(const float4*)(xp + c * 4);
        xv[c*4+0] = v.x; xv[c*4+1] = v.y; xv[c*4+2] = v.z; xv[c*4+3] = v.w;
    }

    float acc[24];
#pragma unroll
    for (int g = 0; g < 24; ++g) acc[g] = 0.0f;
    float sum = 0.0f;

#define BODY(F2)                                                            \
    {                                                                       \
        const float* wt = WaT + (F2) * FF;                                  \
        float dot = ba[F2];                                                 \
        _Pragma("unroll")                                                   \
        for (int f = 0; f < FF; ++f) dot = fmaf(xv[f], wt[f], dot);         \
        const float e = __expf(dot);                                        \
        sum += e;                                                           \
        const float p = xv[F2] * e;                                         \
        const float* wl = Wl + (F2) * 24;                                   \
        _Pragma("unroll")                                                   \
        for (int g = 0; g < 24; ++g) acc[g] = fmaf(p, wl[g], acc[g]);       \
    }

    BODY(0)  BODY(1)  BODY(2)  BODY(3)  BODY(4)  BODY(5)  BODY(6)  BODY(7)
    BODY(8)  BODY(9)  BODY(10) BODY(11) BODY(12) BODY(13) BODY(14) BODY(15)
    BODY(16) BODY(17) BODY(18) BODY(19) BODY(20) BODY(21) BODY(22) BODY(23)
    BODY(24) BODY(25) BODY(26) BODY(27) BODY(28) BODY(29) BODY(30) BODY(31)
#undef BODY

    const float r = fast_rcp(sum);

    float* op = xz + (size_t)tid * 24;
#pragma unroll
    for (int jp = 0; jp < HH; ++jp) {
        float4 v;
        v.x = fmaf(acc[0  + jp], r, bl[0  + jp]);   // i
        v.y = fmaf(acc[6  + jp], r, bl[6  + jp]);   // f
        v.z = fmaf(acc[12 + jp], r, bl[12 + jp]);   // g pre-act
        v.w = fmaf(acc[18 + jp], r, bl[18 + jp]);   // o
        *(float4*)(op + jp * 4) = v;
    }
}

// K2 (unchanged, passing): LSTM scan. 8 lanes/batch, DPP cross-lane,
// W10 in LDS, 12-step-deep prefetch.
__global__ __launch_bounds__(64, 1) void k_scan(
    const float* __restrict__ xz, const float* __restrict__ Ul,
    const float* __restrict__ W10, const float* __restrict__ b10,
    const float* __restrict__ Wo, const float* __restrict__ bo,
    float* __restrict__ out)
{
    const int lane = threadIdx.x;
    const int j = lane & 7;
    const int b = blockIdx.x * 8 + (lane >> 3);
    const bool real = (j < HH);
    const int jc = real ? j : 0;

    __shared__ __align__(16) float w10s[TT * HH * 10 + 64];  // +junk row for t=256 prefetch
    {
        const float2* src = (const float2*)W10;
        float2* dst = (float2*)w10s;
        for (int i = lane; i < (TT * HH * 10) / 2; i += 64) dst[i] = src[i];
    }
    __syncthreads();

    float Ui[8], Uf[8], Ug[8], Uo[8];
#pragma unroll
    for (int m = 0; m < 8; ++m) {
        const int src = j ^ m;
        const bool ok = real && (src < HH);
        const float* row = Ul + (ok ? src : 0) * 24;
        Ui[m] = ok ? row[0  + j] : 0.0f;
        Uf[m] = ok ? row[6  + j] : 0.0f;
        Ug[m] = ok ? row[12 + j] : 0.0f;
        Uo[m] = ok ? row[18 + j] : 0.0f;
    }

    float hl[8];           // ovec = ov*ec of unit (j^m); true h = ovec * r2
    float r2 = 1.0f;
    float c = 0.0f;
    float y[10];
#pragma unroll
    for (int m = 0; m < 8; ++m) hl[m] = 0.0f;
#pragma unroll
    for (int p = 0; p < 10; ++p) y[p] = 0.0f;

    float2 wrow[5];
#pragma unroll
    for (int q = 0; q < 5; ++q) wrow[q] = *(const float2*)(w10s + jc * 10 + q * 2);

    const float* xb = xz + (size_t)b * (TT * 24) + j * 4;

    auto step = [&](const float4 z4, const int t) {
        float di0 = hl[0]*Ui[0], di1 = hl[4]*Ui[4];
        float df0 = hl[0]*Uf[0], df1 = hl[4]*Uf[4];
        float dg0 = hl[0]*Ug[0], dg1 = hl[4]*Ug[4];
        float dq0 = hl[0]*Uo[0], dq1 = hl[4]*Uo[4];
#pragma unroll
        for (int m = 1; m < 4; ++m) {
            di0 = fmaf(hl[m], Ui[m], di0); di1 = fmaf(hl[m+4], Ui[m+4], di1);
            df0 = fmaf(hl[m], Uf[m], df0); df1 = fmaf(hl[m+4], Uf[m+4], df1);
            dg0 = fmaf(hl[m], Ug[m], dg0); dg1 = fmaf(hl[m+4], Ug[m+4], dg1);
            dq0 = fmaf(hl[m], Uo[m], dq0); dq1 = fmaf(hl[m+4], Uo[m+4], dq1);
        }
        const float zi = fmaf(di0 + di1, r2, z4.x);
        const float zf = fmaf(df0 + df1, r2, z4.y);
        const float zg = fmaf(dg0 + dg1, r2, z4.z);
        const float zo = fmaf(dq0 + dq1, r2, z4.w);

        const float iv = sigmoidf(zi);
        const float fv = sigmoidf(zf);
        const float ov = sigmoidf(zo);

        const float eg = real ? __expf(zg) : 0.0f;
        float s1 = eg;
        s1 += dppf<DPP_XOR1>(s1);
        s1 += dppf<DPP_XOR2>(s1);
        s1 += dpp_xor4(s1);
        c = fmaf(fv, c, (iv * eg) * fast_rcp(s1));

        const float cmsk = real ? c : -1e30f;
        float m2 = fmaxf(cmsk, dppf<DPP_XOR1>(cmsk));
        m2 = fmaxf(m2, dppf<DPP_XOR2>(m2));
        m2 = fmaxf(m2, dpp_xor4(m2));
        const float ec = real ? __expf(c - m2) : 0.0f;
        float s2 = ec;
        s2 += dppf<DPP_XOR1>(s2);
        s2 += dppf<DPP_XOR2>(s2);
        s2 += dpp_xor4(s2);

        const float ovec = ov * ec;
        hl[0] = ovec;
        hl[1] = dppf<DPP_XOR1>(ovec);
        hl[2] = dppf<DPP_XOR2>(ovec);
        hl[3] = dppf<DPP_XOR3>(ovec);
        const float h7 = dppf<DPP_HALF>(ovec);
        hl[7] = h7;
        hl[6] = dppf<DPP_XOR1>(h7);
        hl[5] = dppf<DPP_XOR2>(h7);
        hl[4] = dppf<DPP_XOR3>(h7);
        r2 = fast_rcp(s2);
        const float hn = ovec * r2;

        float2 wn[5];
        const int rn = ((t + 1) * HH + jc) * 10;
#pragma unroll
        for (int q = 0; q < 5; ++q) wn[q] = *(const float2*)(w10s + rn + q * 2);
#pragma unroll
        for (int q = 0; q < 5; ++q) {
            y[2*q]   = fmaf(hn, wrow[q].x, y[2*q]);
            y[2*q+1] = fmaf(hn, wrow[q].y, y[2*q+1]);
        }
#pragma unroll
        for (int q = 0; q < 5; ++q) wrow[q] = wn[q];
    };

    float4 A[4], B[4], C[4], D[4];
    const float* xp = xb;

#define LDBLK(Bf, dt0)                                                  \
    { _Pragma("unroll") for (int q = 0; q < 4; ++q)                     \
        Bf[q] = *(const float4*)(xp + (dt0 + q) * 24); }

    LDBLK(A, 0); LDBLK(B, 4); LDBLK(C, 8);

#pragma unroll 1
    for (int it = 0; it < 16; ++it) {
        const int t0 = it * 16;
        LDBLK(D, 12);
        step(A[0], t0 + 0);  step(A[1], t0 + 1);  step(A[2], t0 + 2);  step(A[3], t0 + 3);
        LDBLK(A, 16);
        step(B[0], t0 + 4);  step(B[1], t0 + 5);  step(B[2], t0 + 6);  step(B[3], t0 + 7);
        LDBLK(B, 20);
        step(C[0], t0 + 8);  step(C[1], t0 + 9);  step(C[2], t0 + 10); step(C[3], t0 + 11);
        LDBLK(C, 24);
        step(D[0], t0 + 12); step(D[1], t0 + 13); step(D[2], t0 + 14); step(D[3], t0 + 15);
        xp += 16 * 24;
    }
#undef LDBLK

#pragma unroll
    for (int p = 0; p < 10; ++p) {
        float v = y[p];
        v += dppf<DPP_XOR1>(v);
        v += dppf<DPP_XOR2>(v);
        v += dpp_xor4(v);
        y[p] = v;
    }

    float o8 = bo[j];
#pragma unroll
    for (int p = 0; p < 10; ++p) o8 = fmaf(y[p] + b10[p], Wo[p * 8 + j], o8);
    out[(size_t)b * 8 + j] = o8;
}

extern "C" void kernel_launch(void* const* d_in, const int* in_sizes, int n_in,
                              void* d_out, int out_size, void* d_ws, size_t ws_size,
                              hipStream_t stream) {
    const float* x   = (const float*)d_in[0];
    const float* Wa  = (const float*)d_in[1];
    const float* ba  = (const float*)d_in[2];
    const float* Wl  = (const float*)d_in[3];
    const float* Ul  = (const float*)d_in[4];
    const float* bl  = (const float*)d_in[5];
    const float* W10 = (const float*)d_in[6];
    const float* b10 = (const float*)d_in[7];
    const float* Wo  = (const float*)d_in[8];
    const float* bo  = (const float*)d_in[9];
    float* out = (float*)d_out;
    float* xz  = (float*)d_ws;                     // BB*TT*24*4 = 96 MiB (+ tail slack)
    float* WaT = (float*)((char*)d_ws + (100u << 20));   // 4 KB transposed Wa

    hipLaunchKernelGGL(k_transpose, dim3(1), dim3(256), 0, stream, Wa, WaT);
    hipLaunchKernelGGL(k_attn_xz, dim3(BB * TT / 256), dim3(256), 0, stream,
                       x, WaT, ba, Wl, bl, xz);
    hipLaunchKernelGGL(k_scan, dim3(BB / 8), dim3(64), 0, stream,
                       xz, Ul, W10, b10, Wo, bo, out);
}

// Round 13
// 164.605 us; speedup vs baseline: 2.3305x; 2.3305x over previous
//
#include <hip/hip_runtime.h>

#define BB 4096
#define TT 256
#define FF 32
#define HH 6

#define DPP_XOR1 0xB1   // quad_perm(1,0,3,2)
#define DPP_XOR2 0x4E   // quad_perm(2,3,0,1)
#define DPP_XOR3 0x1B   // quad_perm(3,2,1,0)
#define DPP_HALF 0x141  // row_half_mirror = xor 7 within 8-lane half-rows

__device__ __forceinline__ float fast_rcp(float x) { return __builtin_amdgcn_rcpf(x); }
__device__ __forceinline__ float sigmoidf(float x) { return fast_rcp(1.0f + __expf(-x)); }

template <int CTRL>
__device__ __forceinline__ float dppf(float x) {
    return __int_as_float(__builtin_amdgcn_update_dpp(
        0, __float_as_int(x), CTRL, 0xF, 0xF, true));
}
__device__ __forceinline__ float dpp_xor4(float x) {
    return dppf<DPP_HALF>(dppf<DPP_XOR3>(x));
}

// K1: 4 lanes per (b,t) item; lane q owns features/columns {4i+q, i=0..7}.
// Phase A: partial dots for ALL 32 columns over own 8 features (Wa rows from
//   padded LDS, bank-disjoint across the quad).
// Reduce-scatter butterfly: lane q ends with full dot of column 4ci+q at
//   literal slot ci. exp -> quad-reduced sum.
// Phase B: acc[24] over own 8 features (Wl rows from padded LDS), quad-combine.
// Epilogue: R8-verified cndmask transpose to [unit][i,f,g,o], *1/sum, +bl.
__global__ __launch_bounds__(256, 4) void k_attn_xz(
    const float* __restrict__ x, const float* __restrict__ Wa, const float* __restrict__ ba,
    const float* __restrict__ Wl, const float* __restrict__ bl, float* __restrict__ xz)
{
    __shared__ __align__(16) float wa_s[FF * 36];   // rows padded 32->36 floats
    __shared__ __align__(16) float wl_s[FF * 28];   // rows padded 24->28 floats
    const int lt = threadIdx.x;

    // stage weights into padded LDS (each float4 stays within one source row:
    // 32%4==0 and 24%4==0)
    {
        const float4 v = *(const float4*)(Wa + lt * 4);
        *(float4*)(wa_s + (lt >> 3) * 36 + (lt & 7) * 4) = v;
        if (lt < 192) {
            const float4 w = *(const float4*)(Wl + lt * 4);
            *(float4*)(wl_s + (lt / 6) * 28 + (lt % 6) * 4) = w;
        }
    }
    __syncthreads();

    const int tid = blockIdx.x * 256 + threadIdx.x;
    const int item = tid >> 2;
    const int q = tid & 3;
    const bool b0 = (q & 1) != 0;
    const bool b1 = (q & 2) != 0;
    const float* xp = x + (size_t)item * FF;

    // own features x[4i+q] (quad covers the row exactly once)
    float own[8];
#pragma unroll
    for (int i = 0; i < 8; ++i) own[i] = xp[4 * i + q];

    // Phase A: partial[c] = sum_{own features f} x[f] * Wa[f][c], c = 0..31
    float partial[32];
#pragma unroll
    for (int c = 0; c < 32; ++c) partial[c] = 0.0f;

#define PHA(I) { \
        const float xi = own[I]; \
        const float* wr = wa_s + (4 * (I) + q) * 36; \
        _Pragma("unroll") \
        for (int cc = 0; cc < 8; ++cc) { \
            const float4 w = *(const float4*)(wr + cc * 4); \
            partial[cc*4+0] = fmaf(xi, w.x, partial[cc*4+0]); \
            partial[cc*4+1] = fmaf(xi, w.y, partial[cc*4+1]); \
            partial[cc*4+2] = fmaf(xi, w.z, partial[cc*4+2]); \
            partial[cc*4+3] = fmaf(xi, w.w, partial[cc*4+3]); \
        } }
    PHA(0) PHA(1) PHA(2) PHA(3) PHA(4) PHA(5) PHA(6) PHA(7)
#undef PHA

    // Reduce-scatter: lane q gets full dot of column 4ci+q at slot ci.
    float dotv[8];
#define RSG(CI) { \
        const float p0 = partial[4*(CI)+0], p1 = partial[4*(CI)+1]; \
        const float p2 = partial[4*(CI)+2], p3 = partial[4*(CI)+3]; \
        const float v01 = b0 ? p1 : p0, u01 = b0 ? p0 : p1; \
        const float v23 = b0 ? p3 : p2, u23 = b0 ? p2 : p3; \
        const float r01 = v01 + dppf<DPP_XOR1>(u01); \
        const float r23 = v23 + dppf<DPP_XOR1>(u23); \
        const float vv = b1 ? r23 : r01, uu = b1 ? r01 : r23; \
        dotv[CI] = vv + dppf<DPP_XOR2>(uu); }
    RSG(0) RSG(1) RSG(2) RSG(3) RSG(4) RSG(5) RSG(6) RSG(7)
#undef RSG

    // exp (no max-sub: |s| small, fp32 safe — verified R9-R12) + quad sum
    float e[8];
    float sum = 0.0f;
#pragma unroll
    for (int i = 0; i < 8; ++i) {
        e[i] = __expf(dotv[i] + ba[4 * i + q]);
        sum += e[i];
    }
    sum += dppf<DPP_XOR1>(sum);
    sum += dppf<DPP_XOR2>(sum);

    // Phase B: acc[g] += (x[4i+q]*e[4i+q]) * Wl[4i+q][g]  (gate-major)
    float acc[24];
#pragma unroll
    for (int g = 0; g < 24; ++g) acc[g] = 0.0f;

#define PHB(I) { \
        const float pp = own[I] * e[I]; \
        const float* wr = wl_s + (4 * (I) + q) * 28; \
        _Pragma("unroll") \
        for (int gc = 0; gc < 6; ++gc) { \
            const float4 w = *(const float4*)(wr + gc * 4); \
            acc[gc*4+0] = fmaf(pp, w.x, acc[gc*4+0]); \
            acc[gc*4+1] = fmaf(pp, w.y, acc[gc*4+1]); \
            acc[gc*4+2] = fmaf(pp, w.z, acc[gc*4+2]); \
            acc[gc*4+3] = fmaf(pp, w.w, acc[gc*4+3]); \
        } }
    PHB(0) PHB(1) PHB(2) PHB(3) PHB(4) PHB(5) PHB(6) PHB(7)
#undef PHB

    // quad combine -> all lanes hold full gate-major sums
#pragma unroll
    for (int g = 0; g < 24; ++g) acc[g] += dppf<DPP_XOR1>(acc[g]);
#pragma unroll
    for (int g = 0; g < 24; ++g) acc[g] += dppf<DPP_XOR2>(acc[g]);

    const float r = fast_rcp(sum);

    // epilogue (R8-verified): transpose gate-major -> [unit][i,f,g,o]
    float* op = xz + (size_t)item * 24;
    {
        const float ai = (q == 0) ? acc[0]  : (q == 1) ? acc[1]  : (q == 2) ? acc[2]  : acc[3];
        const float af = (q == 0) ? acc[6]  : (q == 1) ? acc[7]  : (q == 2) ? acc[8]  : acc[9];
        const float ag = (q == 0) ? acc[12] : (q == 1) ? acc[13] : (q == 2) ? acc[14] : acc[15];
        const float ao = (q == 0) ? acc[18] : (q == 1) ? acc[19] : (q == 2) ? acc[20] : acc[21];
        float4 o;
        o.x = fmaf(ai, r, bl[0  + q]);
        o.y = fmaf(af, r, bl[6  + q]);
        o.z = fmaf(ag, r, bl[12 + q]);
        o.w = fmaf(ao, r, bl[18 + q]);
        *(float4*)(op + q * 4) = o;
    }
    if (q < 2) {
        const int jp = 4 + q;
        const float ai = (q == 0) ? acc[4]  : acc[5];
        const float af = (q == 0) ? acc[10] : acc[11];
        const float ag = (q == 0) ? acc[16] : acc[17];
        const float ao = (q == 0) ? acc[22] : acc[23];
        float4 o;
        o.x = fmaf(ai, r, bl[0  + jp]);
        o.y = fmaf(af, r, bl[6  + jp]);
        o.z = fmaf(ag, r, bl[12 + jp]);
        o.w = fmaf(ao, r, bl[18 + jp]);
        *(float4*)(op + jp * 4) = o;
    }
}

// K2 (unchanged, passing): LSTM scan. 8 lanes/batch, DPP cross-lane,
// W10 in LDS, 12-step-deep prefetch.
__global__ __launch_bounds__(64, 1) void k_scan(
    const float* __restrict__ xz, const float* __restrict__ Ul,
    const float* __restrict__ W10, const float* __restrict__ b10,
    const float* __restrict__ Wo, const float* __restrict__ bo,
    float* __restrict__ out)
{
    const int lane = threadIdx.x;
    const int j = lane & 7;
    const int b = blockIdx.x * 8 + (lane >> 3);
    const bool real = (j < HH);
    const int jc = real ? j : 0;

    __shared__ __align__(16) float w10s[TT * HH * 10 + 64];  // +junk row for t=256 prefetch
    {
        const float2* src = (const float2*)W10;
        float2* dst = (float2*)w10s;
        for (int i = lane; i < (TT * HH * 10) / 2; i += 64) dst[i] = src[i];
    }
    __syncthreads();

    float Ui[8], Uf[8], Ug[8], Uo[8];
#pragma unroll
    for (int m = 0; m < 8; ++m) {
        const int src = j ^ m;
        const bool ok = real && (src < HH);
        const float* row = Ul + (ok ? src : 0) * 24;
        Ui[m] = ok ? row[0  + j] : 0.0f;
        Uf[m] = ok ? row[6  + j] : 0.0f;
        Ug[m] = ok ? row[12 + j] : 0.0f;
        Uo[m] = ok ? row[18 + j] : 0.0f;
    }

    float hl[8];           // ovec = ov*ec of unit (j^m); true h = ovec * r2
    float r2 = 1.0f;
    float c = 0.0f;
    float y[10];
#pragma unroll
    for (int m = 0; m < 8; ++m) hl[m] = 0.0f;
#pragma unroll
    for (int p = 0; p < 10; ++p) y[p] = 0.0f;

    float2 wrow[5];
#pragma unroll
    for (int q = 0; q < 5; ++q) wrow[q] = *(const float2*)(w10s + jc * 10 + q * 2);

    const float* xb = xz + (size_t)b * (TT * 24) + j * 4;

    auto step = [&](const float4 z4, const int t) {
        float di0 = hl[0]*Ui[0], di1 = hl[4]*Ui[4];
        float df0 = hl[0]*Uf[0], df1 = hl[4]*Uf[4];
        float dg0 = hl[0]*Ug[0], dg1 = hl[4]*Ug[4];
        float dq0 = hl[0]*Uo[0], dq1 = hl[4]*Uo[4];
#pragma unroll
        for (int m = 1; m < 4; ++m) {
            di0 = fmaf(hl[m], Ui[m], di0); di1 = fmaf(hl[m+4], Ui[m+4], di1);
            df0 = fmaf(hl[m], Uf[m], df0); df1 = fmaf(hl[m+4], Uf[m+4], df1);
            dg0 = fmaf(hl[m], Ug[m], dg0); dg1 = fmaf(hl[m+4], Ug[m+4], dg1);
            dq0 = fmaf(hl[m], Uo[m], dq0); dq1 = fmaf(hl[m+4], Uo[m+4], dq1);
        }
        const float zi = fmaf(di0 + di1, r2, z4.x);
        const float zf = fmaf(df0 + df1, r2, z4.y);
        const float zg = fmaf(dg0 + dg1, r2, z4.z);
        const float zo = fmaf(dq0 + dq1, r2, z4.w);

        const float iv = sigmoidf(zi);
        const float fv = sigmoidf(zf);
        const float ov = sigmoidf(zo);

        const float eg = real ? __expf(zg) : 0.0f;
        float s1 = eg;
        s1 += dppf<DPP_XOR1>(s1);
        s1 += dppf<DPP_XOR2>(s1);
        s1 += dpp_xor4(s1);
        c = fmaf(fv, c, (iv * eg) * fast_rcp(s1));

        const float cmsk = real ? c : -1e30f;
        float m2 = fmaxf(cmsk, dppf<DPP_XOR1>(cmsk));
        m2 = fmaxf(m2, dppf<DPP_XOR2>(m2));
        m2 = fmaxf(m2, dpp_xor4(m2));
        const float ec = real ? __expf(c - m2) : 0.0f;
        float s2 = ec;
        s2 += dppf<DPP_XOR1>(s2);
        s2 += dppf<DPP_XOR2>(s2);
        s2 += dpp_xor4(s2);

        const float ovec = ov * ec;
        hl[0] = ovec;
        hl[1] = dppf<DPP_XOR1>(ovec);
        hl[2] = dppf<DPP_XOR2>(ovec);
        hl[3] = dppf<DPP_XOR3>(ovec);
        const float h7 = dppf<DPP_HALF>(ovec);
        hl[7] = h7;
        hl[6] = dppf<DPP_XOR1>(h7);
        hl[5] = dppf<DPP_XOR2>(h7);
        hl[4] = dppf<DPP_XOR3>(h7);
        r2 = fast_rcp(s2);
        const float hn = ovec * r2;

        float2 wn[5];
        const int rn = ((t + 1) * HH + jc) * 10;
#pragma unroll
        for (int q = 0; q < 5; ++q) wn[q] = *(const float2*)(w10s + rn + q * 2);
#pragma unroll
        for (int q = 0; q < 5; ++q) {
            y[2*q]   = fmaf(hn, wrow[q].x, y[2*q]);
            y[2*q+1] = fmaf(hn, wrow[q].y, y[2*q+1]);
        }
#pragma unroll
        for (int q = 0; q < 5; ++q) wrow[q] = wn[q];
    };

    float4 A[4], B[4], C[4], D[4];
    const float* xp = xb;

#define LDBLK(Bf, dt0)                                                  \
    { _Pragma("unroll") for (int q = 0; q < 4; ++q)                     \
        Bf[q] = *(const float4*)(xp + (dt0 + q) * 24); }

    LDBLK(A, 0); LDBLK(B, 4); LDBLK(C, 8);

#pragma unroll 1
    for (int it = 0; it < 16; ++it) {
        const int t0 = it * 16;
        LDBLK(D, 12);
        step(A[0], t0 + 0);  step(A[1], t0 + 1);  step(A[2], t0 + 2);  step(A[3], t0 + 3);
        LDBLK(A, 16);
        step(B[0], t0 + 4);  step(B[1], t0 + 5);  step(B[2], t0 + 6);  step(B[3], t0 + 7);
        LDBLK(B, 20);
        step(C[0], t0 + 8);  step(C[1], t0 + 9);  step(C[2], t0 + 10); step(C[3], t0 + 11);
        LDBLK(C, 24);
        step(D[0], t0 + 12); step(D[1], t0 + 13); step(D[2], t0 + 14); step(D[3], t0 + 15);
        xp += 16 * 24;
    }
#undef LDBLK

#pragma unroll
    for (int p = 0; p < 10; ++p) {
        float v = y[p];
        v += dppf<DPP_XOR1>(v);
        v += dppf<DPP_XOR2>(v);
        v += dpp_xor4(v);
        y[p] = v;
    }

    float o8 = bo[j];
#pragma unroll
    for (int p = 0; p < 10; ++p) o8 = fmaf(y[p] + b10[p], Wo[p * 8 + j], o8);
    out[(size_t)b * 8 + j] = o8;
}

extern "C" void kernel_launch(void* const* d_in, const int* in_sizes, int n_in,
                              void* d_out, int out_size, void* d_ws, size_t ws_size,
                              hipStream_t stream) {
    const float* x   = (const float*)d_in[0];
    const float* Wa  = (const float*)d_in[1];
    const float* ba  = (const float*)d_in[2];
    const float* Wl  = (const float*)d_in[3];
    const float* Ul  = (const float*)d_in[4];
    const float* bl  = (const float*)d_in[5];
    const float* W10 = (const float*)d_in[6];
    const float* b10 = (const float*)d_in[7];
    const float* Wo  = (const float*)d_in[8];
    const float* bo  = (const float*)d_in[9];
    float* out = (float*)d_out;
    float* xz  = (float*)d_ws;   // BB*TT*24*4 = 96 MiB (+ slack for tail prefetch)

    hipLaunchKernelGGL(k_attn_xz, dim3(BB * TT * 4 / 256), dim3(256), 0, stream,
                       x, Wa, ba, Wl, bl, xz);
    hipLaunchKernelGGL(k_scan, dim3(BB / 8), dim3(64), 0, stream,
                       xz, Ul, W10, b10, Wo, bo, out);
}